// Round 14
// baseline (324.431 us; speedup 1.0000x reference)
//
#include <hip/hip_runtime.h>
#include <math.h>

// Problem constants
#define BN   32768
#define DIM  256
#define KC   1024
#define BN_EPS 1e-5f

// Output layout (floats) in d_out
#define QX_SIZE   (BN * DIM)
#define LOSS0_OFF (QX_SIZE)
#define LOSS1_OFF (QX_SIZE + 1)
#define IDX_OFF   (QX_SIZE + 2)
#define PERP_OFF  (QX_SIZE + 2 + BN)

// Fallback scratch partials in the (later overwritten) QX region of out:
#define PART_V 0             // [NSLICE][BN] slice-min values
#define PART_I (NSLICE * BN) // [NSLICE][BN] slice-argmin indices (as float)
// use_pa path: QX region instead holds pre-packed A fragments (32 MB exact),
// written by k_packA, read by k_main, overwritten with q by k_epi.

// Workspace (float offsets)
#define WS_SUM    0     // 256
#define WS_SUMSQ  256   // 256
#define WS_COUNT  512   // 1
#define WS_LOSS   513   // 1
#define WS_COUNTS 1024  // 1024 (float counts -> perplexity)
#define WS_CNORM  3072  // 1024
#define WS_PK     8192                  // packed B chunks, 262144 floats (1MB)
#define WS_ETX    (8192 + 262144)       // eT [K][D] f32 (fallback only)
#define WS_MINKEY (8192 + 262144 + 262144) // [BN] u64 argmin keys
#define WS_ET_LEG 8192                  // eT offset in legacy layout

#define NSLICE 4
#define SLICEK (KC / NSLICE)            // 256 codes per slice
#define NGRP   (SLICEK / 64)            // 4 code-groups of 64 per slice

typedef short bf16x8  __attribute__((ext_vector_type(8)));
typedef float f32x4   __attribute__((ext_vector_type(4)));
typedef float fvec4   __attribute__((ext_vector_type(4)));
typedef int   int4v   __attribute__((ext_vector_type(4)));
typedef unsigned long long u64;

static __device__ inline unsigned short f2bf(float f) {
    unsigned int u = __float_as_uint(f);
    return (unsigned short)((u + 0x7FFFu + ((u >> 16) & 1u)) >> 16);
}
static __device__ inline fvec4 nt_ld4(const void* p) {
    return __builtin_nontemporal_load((const fvec4*)p);
}
static __device__ inline void nt_st(float* p, float v) {
    __builtin_nontemporal_store(v, p);
}
// order-preserving float -> u32 (for atomicMin argmin keys)
static __device__ inline unsigned enc_f32(float f) {
    unsigned u = __float_as_uint(f);
    return (u & 0x80000000u) ? ~u : (u | 0x80000000u);
}

// ---------------------------------------------------------------- kernel 1
// Blocks 0..255: masked stats. 256..259: cnorm. 260..323: transpose + pack.
__global__ __launch_bounds__(256) void k_pre(const float* __restrict__ x,
                                             const int* __restrict__ mask,
                                             const float* __restrict__ e,
                                             float* __restrict__ ws,
                                             int use_et, int use_pk, int et_off) {
    int t = threadIdx.x;
    int b = blockIdx.x;
    if (b >= 260) {                        // transpose tiles 64d x 64k
        if (!use_et && !use_pk) return;
        int b2 = b - 260;
        int d0 = (b2 >> 4) * 64;
        int k0 = (b2 & 15) * 64;
        __shared__ float tile[64][65];
        int c = t & 63;
        int rq = t >> 6;
        #pragma unroll
        for (int p = 0; p < 16; ++p) {
            int dd = p * 4 + rq;
            tile[dd][c] = e[(size_t)(d0 + dd) * KC + k0 + c];
        }
        __syncthreads();
        if (use_et) {
            #pragma unroll
            for (int p = 0; p < 16; ++p) {
                int kk = p * 4 + rq;
                nt_st(&ws[et_off + (size_t)(k0 + kk) * DIM + d0 + c],
                      tile[c][kk]);
            }
        }
        if (use_pk) {
            // Pack chunk-ordered B (bit-identical truncate split).
            char* pk = (char*)(ws + WS_PK);
            int lane2 = t & 63;
            int fgrp = t >> 6;
            int quad2 = lane2 >> 4, col2 = lane2 & 15;
            int G = b2 & 15;
            #pragma unroll
            for (int p = 0; p < 4; ++p) {
                int fi = fgrp * 4 + p;
                int kcl = fi >> 3;
                int nt = (fi >> 1) & 3;
                int h = fi & 1;
                int kcg = (b2 >> 4) * 2 + kcl;
                bf16x8 ov;
                #pragma unroll
                for (int j = 0; j < 8; ++j) {
                    float v = tile[kcl * 32 + quad2 * 8 + j][nt * 16 + col2];
                    unsigned u = __float_as_uint(v);
                    if (h == 0) {
                        ov[j] = (short)(u >> 16);
                    } else {
                        float lf = v - __uint_as_float(u & 0xffff0000u);
                        ov[j] = (short)(__float_as_uint(lf) >> 16);
                    }
                }
                size_t off = ((size_t)((G * 8 + kcg) * 8 + nt * 2 + h) << 10)
                             + (size_t)lane2 * 16;
                *(bf16x8*)(pk + off) = ov;
            }
        }
        return;
    }
    if (b >= 256) {                        // cnorm
        int k = (b - 256) * 256 + t;
        float acc = 0.f;
        #pragma unroll 8
        for (int d = 0; d < DIM; ++d) {
            float v = e[(size_t)d * KC + k];
            acc = fmaf(v, v, acc);
        }
        ws[WS_CNORM + k] = acc;
        return;
    }
    __shared__ float s4[4 * 256];
    __shared__ float q4[4 * 256];
    __shared__ float cntS[4];
    int c4 = t & 63;
    int rsub = t >> 6;
    float s0=0.f,s1=0.f,s2=0.f,s3=0.f, q0=0.f,q1=0.f,q2=0.f,q3=0.f, cnt=0.f;
    int rbase = b * 4 + rsub;
    for (int i = 0; i < 32; ++i) {
        int r = rbase + i * 1024;
        float m = (float)mask[r];
        fvec4 v = nt_ld4(&x[(size_t)r * DIM + c4 * 4]);
        cnt += m;
        float m0 = m*v.x, m1 = m*v.y, m2 = m*v.z, m3 = m*v.w;
        s0 += m0; s1 += m1; s2 += m2; s3 += m3;
        q0 = fmaf(m0, v.x, q0); q1 = fmaf(m1, v.y, q1);
        q2 = fmaf(m2, v.z, q2); q3 = fmaf(m3, v.w, q3);
    }
    int f = c4 * 4;
    s4[rsub * 256 + f + 0] = s0; s4[rsub * 256 + f + 1] = s1;
    s4[rsub * 256 + f + 2] = s2; s4[rsub * 256 + f + 3] = s3;
    q4[rsub * 256 + f + 0] = q0; q4[rsub * 256 + f + 1] = q1;
    q4[rsub * 256 + f + 2] = q2; q4[rsub * 256 + f + 3] = q3;
    if (c4 == 0) cntS[rsub] = cnt;
    __syncthreads();
    float stot = s4[t] + s4[256 + t] + s4[512 + t] + s4[768 + t];
    float qtot = q4[t] + q4[256 + t] + q4[512 + t] + q4[768 + t];
    atomicAdd(&ws[WS_SUM + t], stot);
    atomicAdd(&ws[WS_SUMSQ + t], qtot);
    if (t == 0)
        atomicAdd(&ws[WS_COUNT], cntS[0] + cntS[1] + cntS[2] + cntS[3]);
}

// ---------------------------------------------------------------- kernel 2a
// Pre-pack A fragments ONCE: compute xb, bit-identical f2bf hi/lo split,
// write MFMA-fragment-ordered A into out's QX region (32 MB).
// Layout: base (rb*8+w)*16384 bytes; frag (kc*2+h)*1024 + lane*16.
__global__ __launch_bounds__(512) void k_packA(
        const float* __restrict__ x, const float* __restrict__ gamma,
        const float* __restrict__ beta, const float* __restrict__ ws,
        float* __restrict__ out) {
    __shared__ float muS[DIM], scS[DIM], btS[DIM];
    const int tid = threadIdx.x;
    const int row0 = blockIdx.x * 128;
    const int w = tid >> 6;
    const int lane = tid & 63;
    const int quad = lane >> 4;
    const int col0 = lane & 15;
    if (tid < 256) {
        float cnt = ws[WS_COUNT];
        float nv = fmaxf(cnt, 1.f);
        float mu = ws[WS_SUM + tid] / nv;
        float var = ws[WS_SUMSQ + tid] / nv - mu * mu;
        var = fmaxf(var, 0.f);
        muS[tid] = mu;
        scS[tid] = rsqrtf(var + BN_EPS) * gamma[tid];
        btS[tid] = beta[tid];
    }
    __syncthreads();
    const float* xr = x + (size_t)(row0 + w * 16 + col0) * DIM;
    char* pa = (char*)out + (size_t)(blockIdx.x * 8 + w) * 16384;
    #pragma unroll
    for (int kc = 0; kc < 8; ++kc) {
        int k0 = kc * 32 + quad * 8;
        fvec4 v0 = nt_ld4(xr + k0);
        fvec4 v1 = nt_ld4(xr + k0 + 4);
        float xv[8] = {v0.x, v0.y, v0.z, v0.w, v1.x, v1.y, v1.z, v1.w};
        bf16x8 hv, lv;
        #pragma unroll
        for (int j = 0; j < 8; ++j) {
            float xb = fmaf(xv[j] - muS[k0 + j], scS[k0 + j], btS[k0 + j]);
            unsigned short h = f2bf(xb);
            float hf = __uint_as_float((unsigned)h << 16);
            hv[j] = (short)h;
            lv[j] = (short)f2bf(xb - hf);
        }
        __builtin_nontemporal_store(hv,
            (bf16x8*)(pa + (kc * 2 + 0) * 1024 + lane * 16));
        __builtin_nontemporal_store(lv,
            (bf16x8*)(pa + (kc * 2 + 1) * 1024 + lane * 16));
    }
}

// ---------------------------------------------------------------- kernel 3
// MFMA main, 4-way codebook-sliced (R12 structure — best measured, 70us).
// 512 threads (8 waves), 128 rows/block, slice = 256 codes. Grid 1024.
// Chunk = 8KB, 4-slot LDS ring, depth-2, vmcnt(2). use_pa: A fragments
// pre-packed in out's QX region. launch_bounds (512,6): reg cap 84
// (usage 64) -> 3 blocks/CU (R12 was 2) — blocks are independent, so
// cross-block overlap hides the stage->barrier->compute bubbles (R13
// showed occupancy dominates intra-block LDS traffic in this structure).
// Cross-slice merge: atomicMin(u64 key) into ws.

#define CHUNK_COMPUTE(slot, kcc)                                             \
    {                                                                        \
        const char* bufb = &Bs[(slot) * 8192];                               \
        __builtin_amdgcn_s_setprio(1);                                       \
        _Pragma("unroll")                                                    \
        for (int nt = 0; nt < 4; ++nt) {                                     \
            bf16x8 bh = *(const bf16x8*)(bufb + (nt * 2 + 0) * 1024 + lane * 16); \
            bf16x8 bl = *(const bf16x8*)(bufb + (nt * 2 + 1) * 1024 + lane * 16); \
            acc[nt] = __builtin_amdgcn_mfma_f32_16x16x32_bf16(ah[kcc], bh, acc[nt], 0, 0, 0); \
            acc[nt] = __builtin_amdgcn_mfma_f32_16x16x32_bf16(ah[kcc], bl, acc[nt], 0, 0, 0); \
            acc[nt] = __builtin_amdgcn_mfma_f32_16x16x32_bf16(al[kcc], bh, acc[nt], 0, 0, 0); \
        }                                                                    \
        __builtin_amdgcn_s_setprio(0);                                       \
    }

#define SCORE_MERGE(gg)                                                      \
    {                                                                        \
        _Pragma("unroll")                                                    \
        for (int r = 0; r < 4; ++r) {                                        \
            float v = 3.4e38f; int ii = 0;                                   \
            _Pragma("unroll")                                                \
            for (int nt = 0; nt < 4; ++nt) {                                 \
                int kl = (gg) * 64 + nt * 16 + col0;                         \
                float sc = fmaf(-2.f, acc[nt][r], cnS[kl]);                  \
                if (sc < v) { v = sc; ii = kl; }                             \
            }                                                                \
            _Pragma("unroll")                                                \
            for (int m2 = 1; m2 < 16; m2 <<= 1) {                            \
                float v2 = __shfl_xor(v, m2, 64);                            \
                int   i2 = __shfl_xor(ii, m2, 64);                           \
                if (v2 < v || (v2 == v && i2 < ii)) { v = v2; ii = i2; }     \
            }                                                                \
            if (v < bv[r] || (v == bv[r] && ii < bi_[r])) {                  \
                bv[r] = v; bi_[r] = ii;                                      \
            }                                                                \
        }                                                                    \
        _Pragma("unroll")                                                    \
        for (int nt = 0; nt < 4; ++nt)                                       \
            acc[nt] = (f32x4){0.f, 0.f, 0.f, 0.f};                           \
    }

__global__ __launch_bounds__(512, 6) void k_main_mfma(
        const float* __restrict__ x, const int* __restrict__ mask,
        const float* __restrict__ e, const float* __restrict__ gamma,
        const float* __restrict__ beta,
        float* __restrict__ ws, float* __restrict__ out,
        int use_pk, int use_mk, int use_pa) {
    __shared__ __align__(16) char Bs[4 * 8192];   // 32 KB B ring
    __shared__ float muS[DIM], scS[DIM], btS[DIM];
    __shared__ float cnS[SLICEK];

    const int tid = threadIdx.x;
    const int rb = blockIdx.x >> 2;
    const int s = blockIdx.x & 3;        // codebook slice
    const int row0 = rb * 128;
    const int w = tid >> 6;              // 0..7
    const int lane = tid & 63;
    const int quad = lane >> 4;
    const int col0 = lane & 15;

    if (!use_pa && tid < 256) {
        float cnt = ws[WS_COUNT];
        float nv = fmaxf(cnt, 1.f);
        float mu = ws[WS_SUM + tid] / nv;
        float var = ws[WS_SUMSQ + tid] / nv - mu * mu;
        var = fmaxf(var, 0.f);
        muS[tid] = mu;
        scS[tid] = rsqrtf(var + BN_EPS) * gamma[tid];
        btS[tid] = beta[tid];
    }
    if (tid < SLICEK)
        cnS[tid] = ws[WS_CNORM + s * SLICEK + tid];
    __syncthreads();

    // ---- A fragments in registers: wave w rows row0+w*16+col0
    bf16x8 ah[8], al[8];
    if (use_pa) {
        const char* pa = (const char*)out + (size_t)(rb * 8 + w) * 16384;
        #pragma unroll
        for (int kc = 0; kc < 8; ++kc) {
            ah[kc] = *(const bf16x8*)(pa + (kc * 2 + 0) * 1024 + lane * 16);
            al[kc] = *(const bf16x8*)(pa + (kc * 2 + 1) * 1024 + lane * 16);
        }
    } else {
        const float* xr = x + (size_t)(row0 + w * 16 + col0) * DIM;
        #pragma unroll
        for (int kc = 0; kc < 8; ++kc) {
            int k0 = kc * 32 + quad * 8;
            fvec4 v0 = nt_ld4(xr + k0);
            fvec4 v1 = nt_ld4(xr + k0 + 4);
            float xv[8] = {v0.x, v0.y, v0.z, v0.w, v1.x, v1.y, v1.z, v1.w};
            bf16x8 hv, lv;
            #pragma unroll
            for (int j = 0; j < 8; ++j) {
                float xb = fmaf(xv[j] - muS[k0 + j], scS[k0 + j], btS[k0 + j]);
                unsigned short h = f2bf(xb);
                float hf = __uint_as_float((unsigned)h << 16);
                hv[j] = (short)h;
                lv[j] = (short)f2bf(xb - hf);
            }
            ah[kc] = hv;
            al[kc] = lv;
        }
    }
    // retire A loads so the counted-vmcnt math sees only stage loads
    asm volatile("s_waitcnt vmcnt(0)" ::: "memory");
    __builtin_amdgcn_sched_barrier(0);

    f32x4 acc[4];
    #pragma unroll
    for (int nt = 0; nt < 4; ++nt)
        acc[nt] = (f32x4){0.f, 0.f, 0.f, 0.f};
    float bv[4] = {3.4e38f, 3.4e38f, 3.4e38f, 3.4e38f};
    int   bi_[4] = {0, 0, 0, 0};

    if (use_pk) {
        const char* pkb = (const char*)(ws + WS_PK)
                          + (size_t)s * (NGRP * 8 * 8192);
        auto stage = [&](int c2, int slot) {
            const char* src = pkb + (size_t)c2 * 8192 + w * 1024 + lane * 16;
            char* dst = &Bs[slot * 8192 + w * 1024];
            __builtin_amdgcn_global_load_lds(
                (const __attribute__((address_space(1))) void*)src,
                (__attribute__((address_space(3))) void*)dst, 16, 0, 0);
        };
        stage(0, 0);
        stage(1, 1);
        for (int g = 0; g < NGRP - 1; ++g) {
            #pragma unroll
            for (int kc = 0; kc < 8; ++kc) {
                stage(g * 8 + kc + 2, (kc + 2) & 3);
                asm volatile("s_waitcnt vmcnt(2)" ::: "memory");
                __builtin_amdgcn_s_barrier();
                __builtin_amdgcn_sched_barrier(0);
                CHUNK_COMPUTE(kc & 3, kc);
            }
            SCORE_MERGE(g);
        }
        {   // last group, counted drain
            #pragma unroll
            for (int kc = 0; kc < 8; ++kc) {
                if (kc < 6) {
                    stage((NGRP - 1) * 8 + kc + 2, (kc + 2) & 3);
                    asm volatile("s_waitcnt vmcnt(2)" ::: "memory");
                } else if (kc == 6) {
                    asm volatile("s_waitcnt vmcnt(1)" ::: "memory");
                } else {
                    asm volatile("s_waitcnt vmcnt(0)" ::: "memory");
                }
                __builtin_amdgcn_s_barrier();
                __builtin_amdgcn_sched_barrier(0);
                CHUNK_COMPUTE(kc & 3, kc);
            }
            SCORE_MERGE(NGRP - 1);
        }
    } else {
        // fallback: scattered loads from e (slice-local), in-reg split
        for (int g = 0; g < NGRP; ++g) {
            #pragma unroll
            for (int kc = 0; kc < 8; ++kc) {
                const float* ep = e + (size_t)(kc * 32 + quad * 8) * KC
                                    + s * SLICEK + g * 64 + col0;
                #pragma unroll
                for (int nt = 0; nt < 4; ++nt) {
                    const float* epn = ep + nt * 16;
                    float bvv[8];
                    #pragma unroll
                    for (int j = 0; j < 8; ++j)
                        bvv[j] = epn[(size_t)j * KC];
                    int4v hw, lw;
                    #pragma unroll
                    for (int p = 0; p < 4; ++p) {
                        unsigned u0 = __float_as_uint(bvv[2 * p]);
                        unsigned u1 = __float_as_uint(bvv[2 * p + 1]);
                        hw[p] = (int)__builtin_amdgcn_perm(u1, u0, 0x07060302u);
                        float l0 = bvv[2 * p]     - __uint_as_float(u0 & 0xffff0000u);
                        float l1 = bvv[2 * p + 1] - __uint_as_float(u1 & 0xffff0000u);
                        lw[p] = (int)__builtin_amdgcn_perm(__float_as_uint(l1),
                                                           __float_as_uint(l0),
                                                           0x07060302u);
                    }
                    bf16x8 bh = __builtin_bit_cast(bf16x8, hw);
                    bf16x8 bl = __builtin_bit_cast(bf16x8, lw);
                    acc[nt] = __builtin_amdgcn_mfma_f32_16x16x32_bf16(ah[kc], bh, acc[nt], 0, 0, 0);
                    acc[nt] = __builtin_amdgcn_mfma_f32_16x16x32_bf16(ah[kc], bl, acc[nt], 0, 0, 0);
                    acc[nt] = __builtin_amdgcn_mfma_f32_16x16x32_bf16(al[kc], bh, acc[nt], 0, 0, 0);
                }
            }
            SCORE_MERGE(g);
        }
    }

    // ---- per-wave result: lanes col0==0 own 4 rows each
    if (col0 == 0) {
        if (use_mk) {
            u64* mk = (u64*)(ws + WS_MINKEY);
            #pragma unroll
            for (int r = 0; r < 4; ++r) {
                int rl = w * 16 + quad * 4 + r;
                u64 key = ((u64)enc_f32(bv[r]) << 32)
                          | (unsigned)(s * SLICEK + bi_[r]);
                atomicMin(&mk[row0 + rl], key);
            }
        } else {
            #pragma unroll
            for (int r = 0; r < 4; ++r) {
                int rl = w * 16 + quad * 4 + r;
                out[PART_V + s * BN + row0 + rl] = bv[r];
                out[PART_I + s * BN + row0 + rl] = (float)(s * SLICEK + bi_[r]);
            }
        }
    }
}

// ---------------------------------------------------------------- kernel 3m
// Fallback only: merge slice partials -> final idx + counts.
__global__ __launch_bounds__(256) void k_merge(const int* __restrict__ mask,
                                               float* __restrict__ ws,
                                               float* __restrict__ out) {
    int row = blockIdx.x * 256 + threadIdx.x;
    float bvv = out[PART_V + row];
    int bii = (int)out[PART_I + row];
    #pragma unroll
    for (int s = 1; s < NSLICE; ++s) {
        float v = out[PART_V + s * BN + row];
        int i = (int)out[PART_I + s * BN + row];
        if (v < bvv || (v == bvv && i < bii)) { bvv = v; bii = i; }
    }
    int m = mask[row];
    out[IDX_OFF + row] = m ? (float)bii : -1.0f;
    if (m) atomicAdd(&ws[WS_COUNTS + bii], 1.0f);
}

// ---------------------------------------------------------------- kernel 3b
// Streaming epilogue, 32 rows/block, grid 1024. use_mk path: decode keys,
// write idx; counts via per-block LDS histogram (hot-address global
// atomics were the ~100us wall under code skew); q-gather from e columns
// with wave-uniform idx-reuse register cache (skew -> most gathers skipped).
__global__ __launch_bounds__(256) void k_epi(
        const float* __restrict__ x, const int* __restrict__ mask,
        const float* __restrict__ e, const float* __restrict__ gamma,
        const float* __restrict__ beta,
        const float* __restrict__ ws, float* __restrict__ out,
        int use_et, int et_off, int use_mk) {
    __shared__ __align__(16) float muS[DIM], scS[DIM], btS[DIM];
    __shared__ int   histC[KC];
    __shared__ float wred[4];
    const int tid = threadIdx.x;
    const int row0 = blockIdx.x * 32;
    const int w = tid >> 6;
    const int lane = tid & 63;
    {
        float cnt = ws[WS_COUNT];
        float nv = fmaxf(cnt, 1.f);
        float mu = ws[WS_SUM + tid] / nv;
        float var = ws[WS_SUMSQ + tid] / nv - mu * mu;
        var = fmaxf(var, 0.f);
        muS[tid] = mu;
        scS[tid] = rsqrtf(var + BN_EPS) * gamma[tid];
        btS[tid] = beta[tid];
    }
    #pragma unroll
    for (int j = 0; j < KC / 256; ++j)
        histC[j * 256 + tid] = 0;
    __syncthreads();

    // this wave's 8 row keys + masks (coalesced, lanes 0..7)
    u64 mykey = 0; int mym = 0;
    if (use_mk && lane < 8) {
        const u64* mk = (const u64*)(ws + WS_MINKEY);
        mykey = mk[row0 + w * 8 + lane];
        mym = mask[row0 + w * 8 + lane];
    }

    const int d0 = lane * 4;
    fvec4 mu4 = *(const fvec4*)&muS[d0];
    fvec4 sc4 = *(const fvec4*)&scS[d0];
    fvec4 bt4 = *(const fvec4*)&btS[d0];
    const float* et = ws + et_off;
    float lacc = 0.f;
    int pidx = -1;
    fvec4 g = (fvec4){0.f, 0.f, 0.f, 0.f};
    #pragma unroll
    for (int rr = 0; rr < 8; ++rr) {
        const int row = row0 + w * 8 + rr;
        int m, idx;
        if (use_mk) {
            u64 k = __shfl(mykey, rr, 64);
            m = __shfl(mym, rr, 64);
            idx = (int)(unsigned)(k & 0xFFFFFFFFull);
            if (lane == 0) {
                out[IDX_OFF + row] = m ? (float)idx : -1.0f;
                if (m) atomicAdd(&histC[idx], 1);
            }
        } else {
            m = mask[row];
            idx = m ? (int)out[IDX_OFF + row] : 0;
        }
        const float fm = (float)m;
        fvec4 xv = nt_ld4(&x[(size_t)row * DIM + d0]);
        if (idx != pidx) {          // wave-uniform branch (idx via shfl)
            if (use_mk || !use_et) {
                g.x = e[(size_t)(d0 + 0) * KC + idx];
                g.y = e[(size_t)(d0 + 1) * KC + idx];
                g.z = e[(size_t)(d0 + 2) * KC + idx];
                g.w = e[(size_t)(d0 + 3) * KC + idx];
            } else {
                g = nt_ld4(&et[(size_t)idx * DIM + d0]);
            }
            pidx = idx;
        }
        fvec4 q;
        float dsum = 0.f;
        #pragma unroll
        for (int i = 0; i < 4; ++i) {
            float xb = fmaf(xv[i] - mu4[i], sc4[i], bt4[i]);
            float diff = xb - g[i];
            dsum = fmaf(diff, diff, dsum);
            q[i] = fm * g[i];
        }
        lacc = fmaf(fm, dsum, lacc);
        __builtin_nontemporal_store(q, (fvec4*)&out[(size_t)row * DIM + d0]);
    }
    #pragma unroll
    for (int off2 = 32; off2 > 0; off2 >>= 1)
        lacc += __shfl_down(lacc, off2, 64);
    if (lane == 0) wred[w] = lacc;
    __syncthreads();
    if (use_mk) {
        #pragma unroll
        for (int j = 0; j < KC / 256; ++j) {
            int c = histC[j * 256 + tid];
            if (c > 0) atomicAdd((float*)&ws[WS_COUNTS + j * 256 + tid],
                                 (float)c);
        }
    }
    if (tid == 0)
        atomicAdd((float*)&ws[WS_LOSS], wred[0] + wred[1] + wred[2] + wred[3]);
}

// ---------------------------------------------------------------- kernel 4
__global__ __launch_bounds__(256) void k_final(const float* __restrict__ ws,
                                               float* __restrict__ out) {
    int t = threadIdx.x;
    __shared__ float wr[4];
    float nv = fmaxf(ws[WS_COUNT], 1.f);
    float acc = 0.f;
    for (int j = t; j < KC; j += 256) {
        float p = ws[WS_COUNTS + j] / nv;
        acc = fmaf(p, logf(p + 1e-10f), acc);
    }
    #pragma unroll
    for (int off = 32; off > 0; off >>= 1) acc += __shfl_down(acc, off, 64);
    if ((t & 63) == 0) wr[t >> 6] = acc;
    __syncthreads();
    if (t == 0) {
        float ent = wr[0] + wr[1] + wr[2] + wr[3];
        float loss = ws[WS_LOSS] / (nv * (float)DIM);
        out[LOSS0_OFF] = loss;
        out[LOSS1_OFF] = loss;
        out[PERP_OFF] = expf(-ent);
    }
}

// ---------------------------------------------------------------- launch
extern "C" void kernel_launch(void* const* d_in, const int* in_sizes, int n_in,
                              void* d_out, int out_size, void* d_ws, size_t ws_size,
                              hipStream_t stream) {
    const float* x     = (const float*)d_in[0];
    const int*   amask = (const int*)d_in[1];
    const float* e     = (const float*)d_in[2];
    const float* gamma = (const float*)d_in[3];
    const float* beta  = (const float*)d_in[4];
    float* out = (float*)d_out;
    float* ws  = (float*)d_ws;

    size_t need_mk = (size_t)(WS_MINKEY + 2 * BN) * sizeof(float);   // ~2.39 MB
    size_t need_pk = (size_t)(WS_ETX + KC * DIM) * sizeof(float);    // ~2.03 MB
    size_t need_et = (size_t)(WS_ET_LEG + KC * DIM) * sizeof(float); // ~1.03 MB
    int use_pk = ws_size >= need_pk;
    int use_mk = use_pk && (ws_size >= need_mk);
    int use_pa = use_pk && use_mk;   // pre-packed A lives in out's QX region
    int use_et = use_mk ? 0 : (use_pk ? 1 : (ws_size >= need_et ? 1 : 0));
    int et_off = use_pk ? WS_ETX : WS_ET_LEG;

    (void)hipMemsetAsync(d_ws, 0, 32768, stream);
    if (use_mk)
        (void)hipMemsetAsync((char*)d_ws + (size_t)WS_MINKEY * 4, 0xFF,
                             (size_t)BN * 8, stream);

    k_pre<<<324, 256, 0, stream>>>(x, amask, e, ws, use_et, use_pk, et_off);
    if (use_pa)
        k_packA<<<BN / 128, 512, 0, stream>>>(x, gamma, beta, ws, out);
    k_main_mfma<<<256 * NSLICE, 512, 0, stream>>>(x, amask, e, gamma, beta, ws,
                                                  out, use_pk, use_mk, use_pa);
    if (!use_mk)
        k_merge<<<BN / 256, 256, 0, stream>>>(amask, ws, out);
    k_epi<<<BN / 32, 256, 0, stream>>>(x, amask, e, gamma, beta, ws, out,
                                       use_et, et_off, use_mk);
    k_final<<<1, 256, 0, stream>>>(ws, out);
}

// Round 15
// 212.279 us; speedup vs baseline: 1.5283x; 1.5283x over previous
//
#include <hip/hip_runtime.h>
#include <math.h>

// Problem constants
#define BN   32768
#define DIM  256
#define KC   1024
#define BN_EPS 1e-5f

// Output layout (floats) in d_out
#define QX_SIZE   (BN * DIM)
#define LOSS0_OFF (QX_SIZE)
#define LOSS1_OFF (QX_SIZE + 1)
#define IDX_OFF   (QX_SIZE + 2)
#define PERP_OFF  (QX_SIZE + 2 + BN)

// Fallback scratch partials in the (later overwritten) QX region of out:
#define PART_V 0             // [NSLICE][BN] slice-min values
#define PART_I (NSLICE * BN) // [NSLICE][BN] slice-argmin indices (as float)
// use_pa path: QX region instead holds pre-packed A fragments (32 MB exact),
// written by k_packA, read by k_main, overwritten with q by k_epi.

// Workspace (float offsets)
#define WS_SUM    0     // 256
#define WS_SUMSQ  256   // 256
#define WS_COUNT  512   // 1
#define WS_LOSS   513   // 1
#define WS_COUNTS 1024  // 1024 (float counts -> perplexity)
#define WS_CNORM  3072  // 1024
#define WS_PK     8192                  // packed B chunks, 262144 floats (1MB)
#define WS_ETX    (8192 + 262144)       // eT [K][D] f32 (fallback only)
#define WS_MINKEY (8192 + 262144 + 262144) // [BN] u64 argmin keys
#define WS_XQ     (WS_MINKEY + 2 * BN)  // [BN] per-row |xb|^2 (fp32)
#define WS_ET_LEG 8192                  // eT offset in legacy layout

#define NSLICE 4
#define SLICEK (KC / NSLICE)            // 256 codes per slice
#define NGRP   (SLICEK / 64)            // 4 code-groups of 64 per slice

typedef short bf16x8  __attribute__((ext_vector_type(8)));
typedef float f32x4   __attribute__((ext_vector_type(4)));
typedef float fvec4   __attribute__((ext_vector_type(4)));
typedef int   int4v   __attribute__((ext_vector_type(4)));
typedef unsigned long long u64;

static __device__ inline unsigned short f2bf(float f) {
    unsigned int u = __float_as_uint(f);
    return (unsigned short)((u + 0x7FFFu + ((u >> 16) & 1u)) >> 16);
}
static __device__ inline fvec4 nt_ld4(const void* p) {
    return __builtin_nontemporal_load((const fvec4*)p);
}
static __device__ inline void nt_st(float* p, float v) {
    __builtin_nontemporal_store(v, p);
}
// order-preserving float <-> u32 (for atomicMin argmin keys)
static __device__ inline unsigned enc_f32(float f) {
    unsigned u = __float_as_uint(f);
    return (u & 0x80000000u) ? ~u : (u | 0x80000000u);
}
static __device__ inline float dec_f32(unsigned k) {
    return __uint_as_float((k & 0x80000000u) ? (k ^ 0x80000000u) : ~k);
}

// ---------------------------------------------------------------- kernel 1
// Blocks 0..255: masked stats. 256..259: cnorm. 260..323: transpose + pack.
__global__ __launch_bounds__(256) void k_pre(const float* __restrict__ x,
                                             const int* __restrict__ mask,
                                             const float* __restrict__ e,
                                             float* __restrict__ ws,
                                             int use_et, int use_pk, int et_off) {
    int t = threadIdx.x;
    int b = blockIdx.x;
    if (b >= 260) {                        // transpose tiles 64d x 64k
        if (!use_et && !use_pk) return;
        int b2 = b - 260;
        int d0 = (b2 >> 4) * 64;
        int k0 = (b2 & 15) * 64;
        __shared__ float tile[64][65];
        int c = t & 63;
        int rq = t >> 6;
        #pragma unroll
        for (int p = 0; p < 16; ++p) {
            int dd = p * 4 + rq;
            tile[dd][c] = e[(size_t)(d0 + dd) * KC + k0 + c];
        }
        __syncthreads();
        if (use_et) {
            #pragma unroll
            for (int p = 0; p < 16; ++p) {
                int kk = p * 4 + rq;
                nt_st(&ws[et_off + (size_t)(k0 + kk) * DIM + d0 + c],
                      tile[c][kk]);
            }
        }
        if (use_pk) {
            // Pack chunk-ordered B (bit-identical truncate split).
            char* pk = (char*)(ws + WS_PK);
            int lane2 = t & 63;
            int fgrp = t >> 6;
            int quad2 = lane2 >> 4, col2 = lane2 & 15;
            int G = b2 & 15;
            #pragma unroll
            for (int p = 0; p < 4; ++p) {
                int fi = fgrp * 4 + p;
                int kcl = fi >> 3;
                int nt = (fi >> 1) & 3;
                int h = fi & 1;
                int kcg = (b2 >> 4) * 2 + kcl;
                bf16x8 ov;
                #pragma unroll
                for (int j = 0; j < 8; ++j) {
                    float v = tile[kcl * 32 + quad2 * 8 + j][nt * 16 + col2];
                    unsigned u = __float_as_uint(v);
                    if (h == 0) {
                        ov[j] = (short)(u >> 16);
                    } else {
                        float lf = v - __uint_as_float(u & 0xffff0000u);
                        ov[j] = (short)(__float_as_uint(lf) >> 16);
                    }
                }
                size_t off = ((size_t)((G * 8 + kcg) * 8 + nt * 2 + h) << 10)
                             + (size_t)lane2 * 16;
                *(bf16x8*)(pk + off) = ov;
            }
        }
        return;
    }
    if (b >= 256) {                        // cnorm
        int k = (b - 256) * 256 + t;
        float acc = 0.f;
        #pragma unroll 8
        for (int d = 0; d < DIM; ++d) {
            float v = e[(size_t)d * KC + k];
            acc = fmaf(v, v, acc);
        }
        ws[WS_CNORM + k] = acc;
        return;
    }
    __shared__ float s4[4 * 256];
    __shared__ float q4[4 * 256];
    __shared__ float cntS[4];
    int c4 = t & 63;
    int rsub = t >> 6;
    float s0=0.f,s1=0.f,s2=0.f,s3=0.f, q0=0.f,q1=0.f,q2=0.f,q3=0.f, cnt=0.f;
    int rbase = b * 4 + rsub;
    for (int i = 0; i < 32; ++i) {
        int r = rbase + i * 1024;
        float m = (float)mask[r];
        fvec4 v = nt_ld4(&x[(size_t)r * DIM + c4 * 4]);
        cnt += m;
        float m0 = m*v.x, m1 = m*v.y, m2 = m*v.z, m3 = m*v.w;
        s0 += m0; s1 += m1; s2 += m2; s3 += m3;
        q0 = fmaf(m0, v.x, q0); q1 = fmaf(m1, v.y, q1);
        q2 = fmaf(m2, v.z, q2); q3 = fmaf(m3, v.w, q3);
    }
    int f = c4 * 4;
    s4[rsub * 256 + f + 0] = s0; s4[rsub * 256 + f + 1] = s1;
    s4[rsub * 256 + f + 2] = s2; s4[rsub * 256 + f + 3] = s3;
    q4[rsub * 256 + f + 0] = q0; q4[rsub * 256 + f + 1] = q1;
    q4[rsub * 256 + f + 2] = q2; q4[rsub * 256 + f + 3] = q3;
    if (c4 == 0) cntS[rsub] = cnt;
    __syncthreads();
    float stot = s4[t] + s4[256 + t] + s4[512 + t] + s4[768 + t];
    float qtot = q4[t] + q4[256 + t] + q4[512 + t] + q4[768 + t];
    atomicAdd(&ws[WS_SUM + t], stot);
    atomicAdd(&ws[WS_SUMSQ + t], qtot);
    if (t == 0)
        atomicAdd(&ws[WS_COUNT], cntS[0] + cntS[1] + cntS[2] + cntS[3]);
}

// ---------------------------------------------------------------- kernel 2a
// Pre-pack A fragments ONCE: compute xb, bit-identical f2bf hi/lo split,
// write MFMA-fragment-ordered A into out's QX region (32 MB). Also (use_xq)
// accumulate per-row |xb|^2 (fp32, pre-rounding) into ws so k_epi's loss
// needs NO x re-read: loss_row = |xb|^2 + (|q|^2 - 2<xb,q>) = xq + score.
__global__ __launch_bounds__(512) void k_packA(
        const float* __restrict__ x, const float* __restrict__ gamma,
        const float* __restrict__ beta, float* __restrict__ ws,
        float* __restrict__ out, int use_xq) {
    __shared__ float muS[DIM], scS[DIM], btS[DIM];
    const int tid = threadIdx.x;
    const int row0 = blockIdx.x * 128;
    const int w = tid >> 6;
    const int lane = tid & 63;
    const int quad = lane >> 4;
    const int col0 = lane & 15;
    if (tid < 256) {
        float cnt = ws[WS_COUNT];
        float nv = fmaxf(cnt, 1.f);
        float mu = ws[WS_SUM + tid] / nv;
        float var = ws[WS_SUMSQ + tid] / nv - mu * mu;
        var = fmaxf(var, 0.f);
        muS[tid] = mu;
        scS[tid] = rsqrtf(var + BN_EPS) * gamma[tid];
        btS[tid] = beta[tid];
    }
    __syncthreads();
    const float* xr = x + (size_t)(row0 + w * 16 + col0) * DIM;
    char* pa = (char*)out + (size_t)(blockIdx.x * 8 + w) * 16384;
    float xq = 0.f;
    #pragma unroll
    for (int kc = 0; kc < 8; ++kc) {
        int k0 = kc * 32 + quad * 8;
        fvec4 v0 = nt_ld4(xr + k0);
        fvec4 v1 = nt_ld4(xr + k0 + 4);
        float xv[8] = {v0.x, v0.y, v0.z, v0.w, v1.x, v1.y, v1.z, v1.w};
        bf16x8 hv, lv;
        #pragma unroll
        for (int j = 0; j < 8; ++j) {
            float xb = fmaf(xv[j] - muS[k0 + j], scS[k0 + j], btS[k0 + j]);
            xq = fmaf(xb, xb, xq);
            unsigned short h = f2bf(xb);
            float hf = __uint_as_float((unsigned)h << 16);
            hv[j] = (short)h;
            lv[j] = (short)f2bf(xb - hf);
        }
        __builtin_nontemporal_store(hv,
            (bf16x8*)(pa + (kc * 2 + 0) * 1024 + lane * 16));
        __builtin_nontemporal_store(lv,
            (bf16x8*)(pa + (kc * 2 + 1) * 1024 + lane * 16));
    }
    if (use_xq) {
        // full-row |xb|^2: sum across the 4 quads sharing a row
        xq += __shfl_xor(xq, 16, 64);
        xq += __shfl_xor(xq, 32, 64);
        if (quad == 0)
            ws[WS_XQ + row0 + w * 16 + col0] = xq;
    }
}

// ---------------------------------------------------------------- kernel 3
// MFMA main, 4-way codebook-sliced (R12 structure — best measured, 70us;
// R13 code-split and R14 (512,6) both regressed: 2 blocks/CU at (512,4)
// with VGPR=64 is the feasibility notch — fewer regs spills, more regs
// drops to 1 block/CU). 512 threads, 128 rows/block, slice = 256 codes.
// Grid 1024. Chunk = 8KB, 4-slot LDS ring, depth-2, vmcnt(2). use_pa: A
// pre-packed in out's QX region. Cross-slice merge: atomicMin(u64 key).

#define CHUNK_COMPUTE(slot, kcc)                                             \
    {                                                                        \
        const char* bufb = &Bs[(slot) * 8192];                               \
        __builtin_amdgcn_s_setprio(1);                                       \
        _Pragma("unroll")                                                    \
        for (int nt = 0; nt < 4; ++nt) {                                     \
            bf16x8 bh = *(const bf16x8*)(bufb + (nt * 2 + 0) * 1024 + lane * 16); \
            bf16x8 bl = *(const bf16x8*)(bufb + (nt * 2 + 1) * 1024 + lane * 16); \
            acc[nt] = __builtin_amdgcn_mfma_f32_16x16x32_bf16(ah[kcc], bh, acc[nt], 0, 0, 0); \
            acc[nt] = __builtin_amdgcn_mfma_f32_16x16x32_bf16(ah[kcc], bl, acc[nt], 0, 0, 0); \
            acc[nt] = __builtin_amdgcn_mfma_f32_16x16x32_bf16(al[kcc], bh, acc[nt], 0, 0, 0); \
        }                                                                    \
        __builtin_amdgcn_s_setprio(0);                                       \
    }

#define SCORE_MERGE(gg)                                                      \
    {                                                                        \
        _Pragma("unroll")                                                    \
        for (int r = 0; r < 4; ++r) {                                        \
            float v = 3.4e38f; int ii = 0;                                   \
            _Pragma("unroll")                                                \
            for (int nt = 0; nt < 4; ++nt) {                                 \
                int kl = (gg) * 64 + nt * 16 + col0;                         \
                float sc = fmaf(-2.f, acc[nt][r], cnS[kl]);                  \
                if (sc < v) { v = sc; ii = kl; }                             \
            }                                                                \
            _Pragma("unroll")                                                \
            for (int m2 = 1; m2 < 16; m2 <<= 1) {                            \
                float v2 = __shfl_xor(v, m2, 64);                            \
                int   i2 = __shfl_xor(ii, m2, 64);                           \
                if (v2 < v || (v2 == v && i2 < ii)) { v = v2; ii = i2; }     \
            }                                                                \
            if (v < bv[r] || (v == bv[r] && ii < bi_[r])) {                  \
                bv[r] = v; bi_[r] = ii;                                      \
            }                                                                \
        }                                                                    \
        _Pragma("unroll")                                                    \
        for (int nt = 0; nt < 4; ++nt)                                       \
            acc[nt] = (f32x4){0.f, 0.f, 0.f, 0.f};                           \
    }

__global__ __launch_bounds__(512, 4) void k_main_mfma(
        const float* __restrict__ x, const int* __restrict__ mask,
        const float* __restrict__ e, const float* __restrict__ gamma,
        const float* __restrict__ beta,
        float* __restrict__ ws, float* __restrict__ out,
        int use_pk, int use_mk, int use_pa) {
    __shared__ __align__(16) char Bs[4 * 8192];   // 32 KB B ring
    __shared__ float muS[DIM], scS[DIM], btS[DIM];
    __shared__ float cnS[SLICEK];

    const int tid = threadIdx.x;
    const int rb = blockIdx.x >> 2;
    const int s = blockIdx.x & 3;        // codebook slice
    const int row0 = rb * 128;
    const int w = tid >> 6;              // 0..7
    const int lane = tid & 63;
    const int quad = lane >> 4;
    const int col0 = lane & 15;

    if (!use_pa && tid < 256) {
        float cnt = ws[WS_COUNT];
        float nv = fmaxf(cnt, 1.f);
        float mu = ws[WS_SUM + tid] / nv;
        float var = ws[WS_SUMSQ + tid] / nv - mu * mu;
        var = fmaxf(var, 0.f);
        muS[tid] = mu;
        scS[tid] = rsqrtf(var + BN_EPS) * gamma[tid];
        btS[tid] = beta[tid];
    }
    if (tid < SLICEK)
        cnS[tid] = ws[WS_CNORM + s * SLICEK + tid];
    __syncthreads();

    // ---- A fragments in registers: wave w rows row0+w*16+col0
    bf16x8 ah[8], al[8];
    if (use_pa) {
        const char* pa = (const char*)out + (size_t)(rb * 8 + w) * 16384;
        #pragma unroll
        for (int kc = 0; kc < 8; ++kc) {
            ah[kc] = *(const bf16x8*)(pa + (kc * 2 + 0) * 1024 + lane * 16);
            al[kc] = *(const bf16x8*)(pa + (kc * 2 + 1) * 1024 + lane * 16);
        }
    } else {
        const float* xr = x + (size_t)(row0 + w * 16 + col0) * DIM;
        #pragma unroll
        for (int kc = 0; kc < 8; ++kc) {
            int k0 = kc * 32 + quad * 8;
            fvec4 v0 = nt_ld4(xr + k0);
            fvec4 v1 = nt_ld4(xr + k0 + 4);
            float xv[8] = {v0.x, v0.y, v0.z, v0.w, v1.x, v1.y, v1.z, v1.w};
            bf16x8 hv, lv;
            #pragma unroll
            for (int j = 0; j < 8; ++j) {
                float xb = fmaf(xv[j] - muS[k0 + j], scS[k0 + j], btS[k0 + j]);
                unsigned short h = f2bf(xb);
                float hf = __uint_as_float((unsigned)h << 16);
                hv[j] = (short)h;
                lv[j] = (short)f2bf(xb - hf);
            }
            ah[kc] = hv;
            al[kc] = lv;
        }
    }
    // retire A loads so the counted-vmcnt math sees only stage loads
    asm volatile("s_waitcnt vmcnt(0)" ::: "memory");
    __builtin_amdgcn_sched_barrier(0);

    f32x4 acc[4];
    #pragma unroll
    for (int nt = 0; nt < 4; ++nt)
        acc[nt] = (f32x4){0.f, 0.f, 0.f, 0.f};
    float bv[4] = {3.4e38f, 3.4e38f, 3.4e38f, 3.4e38f};
    int   bi_[4] = {0, 0, 0, 0};

    if (use_pk) {
        const char* pkb = (const char*)(ws + WS_PK)
                          + (size_t)s * (NGRP * 8 * 8192);
        auto stage = [&](int c2, int slot) {
            const char* src = pkb + (size_t)c2 * 8192 + w * 1024 + lane * 16;
            char* dst = &Bs[slot * 8192 + w * 1024];
            __builtin_amdgcn_global_load_lds(
                (const __attribute__((address_space(1))) void*)src,
                (__attribute__((address_space(3))) void*)dst, 16, 0, 0);
        };
        stage(0, 0);
        stage(1, 1);
        for (int g = 0; g < NGRP - 1; ++g) {
            #pragma unroll
            for (int kc = 0; kc < 8; ++kc) {
                stage(g * 8 + kc + 2, (kc + 2) & 3);
                asm volatile("s_waitcnt vmcnt(2)" ::: "memory");
                __builtin_amdgcn_s_barrier();
                __builtin_amdgcn_sched_barrier(0);
                CHUNK_COMPUTE(kc & 3, kc);
            }
            SCORE_MERGE(g);
        }
        {   // last group, counted drain
            #pragma unroll
            for (int kc = 0; kc < 8; ++kc) {
                if (kc < 6) {
                    stage((NGRP - 1) * 8 + kc + 2, (kc + 2) & 3);
                    asm volatile("s_waitcnt vmcnt(2)" ::: "memory");
                } else if (kc == 6) {
                    asm volatile("s_waitcnt vmcnt(1)" ::: "memory");
                } else {
                    asm volatile("s_waitcnt vmcnt(0)" ::: "memory");
                }
                __builtin_amdgcn_s_barrier();
                __builtin_amdgcn_sched_barrier(0);
                CHUNK_COMPUTE(kc & 3, kc);
            }
            SCORE_MERGE(NGRP - 1);
        }
    } else {
        // fallback: scattered loads from e (slice-local), in-reg split
        for (int g = 0; g < NGRP; ++g) {
            #pragma unroll
            for (int kc = 0; kc < 8; ++kc) {
                const float* ep = e + (size_t)(kc * 32 + quad * 8) * KC
                                    + s * SLICEK + g * 64 + col0;
                #pragma unroll
                for (int nt = 0; nt < 4; ++nt) {
                    const float* epn = ep + nt * 16;
                    float bvv[8];
                    #pragma unroll
                    for (int j = 0; j < 8; ++j)
                        bvv[j] = epn[(size_t)j * KC];
                    int4v hw, lw;
                    #pragma unroll
                    for (int p = 0; p < 4; ++p) {
                        unsigned u0 = __float_as_uint(bvv[2 * p]);
                        unsigned u1 = __float_as_uint(bvv[2 * p + 1]);
                        hw[p] = (int)__builtin_amdgcn_perm(u1, u0, 0x07060302u);
                        float l0 = bvv[2 * p]     - __uint_as_float(u0 & 0xffff0000u);
                        float l1 = bvv[2 * p + 1] - __uint_as_float(u1 & 0xffff0000u);
                        lw[p] = (int)__builtin_amdgcn_perm(__float_as_uint(l1),
                                                           __float_as_uint(l0),
                                                           0x07060302u);
                    }
                    bf16x8 bh = __builtin_bit_cast(bf16x8, hw);
                    bf16x8 bl = __builtin_bit_cast(bf16x8, lw);
                    acc[nt] = __builtin_amdgcn_mfma_f32_16x16x32_bf16(ah[kc], bh, acc[nt], 0, 0, 0);
                    acc[nt] = __builtin_amdgcn_mfma_f32_16x16x32_bf16(ah[kc], bl, acc[nt], 0, 0, 0);
                    acc[nt] = __builtin_amdgcn_mfma_f32_16x16x32_bf16(al[kc], bh, acc[nt], 0, 0, 0);
                }
            }
            SCORE_MERGE(g);
        }
    }

    // ---- per-wave result: lanes col0==0 own 4 rows each
    if (col0 == 0) {
        if (use_mk) {
            u64* mk = (u64*)(ws + WS_MINKEY);
            #pragma unroll
            for (int r = 0; r < 4; ++r) {
                int rl = w * 16 + quad * 4 + r;
                u64 key = ((u64)enc_f32(bv[r]) << 32)
                          | (unsigned)(s * SLICEK + bi_[r]);
                atomicMin(&mk[row0 + rl], key);
            }
        } else {
            #pragma unroll
            for (int r = 0; r < 4; ++r) {
                int rl = w * 16 + quad * 4 + r;
                out[PART_V + s * BN + row0 + rl] = bv[r];
                out[PART_I + s * BN + row0 + rl] = (float)(s * SLICEK + bi_[r]);
            }
        }
    }
}

// ---------------------------------------------------------------- kernel 3m
// Fallback only: merge slice partials -> final idx + counts.
__global__ __launch_bounds__(256) void k_merge(const int* __restrict__ mask,
                                               float* __restrict__ ws,
                                               float* __restrict__ out) {
    int row = blockIdx.x * 256 + threadIdx.x;
    float bvv = out[PART_V + row];
    int bii = (int)out[PART_I + row];
    #pragma unroll
    for (int s = 1; s < NSLICE; ++s) {
        float v = out[PART_V + s * BN + row];
        int i = (int)out[PART_I + s * BN + row];
        if (v < bvv || (v == bvv && i < bii)) { bvv = v; bii = i; }
    }
    int m = mask[row];
    out[IDX_OFF + row] = m ? (float)bii : -1.0f;
    if (m) atomicAdd(&ws[WS_COUNTS + bii], 1.0f);
}

// ---------------------------------------------------------------- kernel 3b
// Streaming epilogue, 32 rows/block, grid 1024. use_xq path: NO x re-read —
// loss_row = xq[row] + dec(score); only keys/mask/xq reads + broadcast
// e-gather + NT q-write. Counts via per-block LDS histogram (hot-address
// global atomics were the ~100us wall); q-gather idx-reuse cache.
__global__ __launch_bounds__(256) void k_epi(
        const float* __restrict__ x, const int* __restrict__ mask,
        const float* __restrict__ e, const float* __restrict__ gamma,
        const float* __restrict__ beta,
        const float* __restrict__ ws, float* __restrict__ out,
        int use_et, int et_off, int use_mk, int use_xq) {
    __shared__ __align__(16) float muS[DIM], scS[DIM], btS[DIM];
    __shared__ int   histC[KC];
    __shared__ float wred[4];
    const int tid = threadIdx.x;
    const int row0 = blockIdx.x * 32;
    const int w = tid >> 6;
    const int lane = tid & 63;
    if (!use_xq) {
        float cnt = ws[WS_COUNT];
        float nv = fmaxf(cnt, 1.f);
        float mu = ws[WS_SUM + tid] / nv;
        float var = ws[WS_SUMSQ + tid] / nv - mu * mu;
        var = fmaxf(var, 0.f);
        muS[tid] = mu;
        scS[tid] = rsqrtf(var + BN_EPS) * gamma[tid];
        btS[tid] = beta[tid];
    }
    #pragma unroll
    for (int j = 0; j < KC / 256; ++j)
        histC[j * 256 + tid] = 0;
    __syncthreads();

    // this wave's 8 row keys + masks (+xq) (coalesced, lanes 0..7)
    u64 mykey = 0; int mym = 0; float myxq = 0.f;
    if (use_mk && lane < 8) {
        const u64* mk = (const u64*)(ws + WS_MINKEY);
        mykey = mk[row0 + w * 8 + lane];
        mym = mask[row0 + w * 8 + lane];
        if (use_xq) myxq = ws[WS_XQ + row0 + w * 8 + lane];
    }

    const int d0 = lane * 4;
    const float* et = ws + et_off;
    float lacc = 0.f;
    int pidx = -1;
    fvec4 g = (fvec4){0.f, 0.f, 0.f, 0.f};
    if (use_xq) {
        // ---- no-x path: loss from xq + decoded score
        #pragma unroll
        for (int rr = 0; rr < 8; ++rr) {
            const int row = row0 + w * 8 + rr;
            u64 k = __shfl(mykey, rr, 64);
            int m = __shfl(mym, rr, 64);
            int idx = (int)(unsigned)(k & 0xFFFFFFFFull);
            if (lane == 0) {
                out[IDX_OFF + row] = m ? (float)idx : -1.0f;
                if (m) {
                    atomicAdd(&histC[idx], 1);
                    float score = dec_f32((unsigned)(k >> 32));
                    lacc += __shfl(myxq, rr, 64) + score;
                }
            }
            if (idx != pidx) {          // wave-uniform (idx via shfl)
                g.x = e[(size_t)(d0 + 0) * KC + idx];
                g.y = e[(size_t)(d0 + 1) * KC + idx];
                g.z = e[(size_t)(d0 + 2) * KC + idx];
                g.w = e[(size_t)(d0 + 3) * KC + idx];
                pidx = idx;
            }
            const float fm = (float)m;
            fvec4 q = (fvec4){fm * g.x, fm * g.y, fm * g.z, fm * g.w};
            __builtin_nontemporal_store(q,
                (fvec4*)&out[(size_t)row * DIM + d0]);
        }
        if (lane == 0) wred[w] = lacc;
    } else {
        fvec4 mu4 = *(const fvec4*)&muS[d0];
        fvec4 sc4 = *(const fvec4*)&scS[d0];
        fvec4 bt4 = *(const fvec4*)&btS[d0];
        #pragma unroll
        for (int rr = 0; rr < 8; ++rr) {
            const int row = row0 + w * 8 + rr;
            int m, idx;
            if (use_mk) {
                u64 k = __shfl(mykey, rr, 64);
                m = __shfl(mym, rr, 64);
                idx = (int)(unsigned)(k & 0xFFFFFFFFull);
                if (lane == 0) {
                    out[IDX_OFF + row] = m ? (float)idx : -1.0f;
                    if (m) atomicAdd(&histC[idx], 1);
                }
            } else {
                m = mask[row];
                idx = m ? (int)out[IDX_OFF + row] : 0;
            }
            const float fm = (float)m;
            fvec4 xv = nt_ld4(&x[(size_t)row * DIM + d0]);
            if (idx != pidx) {
                if (use_mk || !use_et) {
                    g.x = e[(size_t)(d0 + 0) * KC + idx];
                    g.y = e[(size_t)(d0 + 1) * KC + idx];
                    g.z = e[(size_t)(d0 + 2) * KC + idx];
                    g.w = e[(size_t)(d0 + 3) * KC + idx];
                } else {
                    g = nt_ld4(&et[(size_t)idx * DIM + d0]);
                }
                pidx = idx;
            }
            fvec4 q;
            float dsum = 0.f;
            #pragma unroll
            for (int i = 0; i < 4; ++i) {
                float xb = fmaf(xv[i] - mu4[i], sc4[i], bt4[i]);
                float diff = xb - g[i];
                dsum = fmaf(diff, diff, dsum);
                q[i] = fm * g[i];
            }
            lacc = fmaf(fm, dsum, lacc);
            __builtin_nontemporal_store(q,
                (fvec4*)&out[(size_t)row * DIM + d0]);
        }
        #pragma unroll
        for (int off2 = 32; off2 > 0; off2 >>= 1)
            lacc += __shfl_down(lacc, off2, 64);
        if (lane == 0) wred[w] = lacc;
    }
    __syncthreads();
    if (use_mk) {
        #pragma unroll
        for (int j = 0; j < KC / 256; ++j) {
            int c = histC[j * 256 + tid];
            if (c > 0) atomicAdd((float*)&ws[WS_COUNTS + j * 256 + tid],
                                 (float)c);
        }
    }
    if (tid == 0)
        atomicAdd((float*)&ws[WS_LOSS], wred[0] + wred[1] + wred[2] + wred[3]);
}

// ---------------------------------------------------------------- kernel 4
__global__ __launch_bounds__(256) void k_final(const float* __restrict__ ws,
                                               float* __restrict__ out) {
    int t = threadIdx.x;
    __shared__ float wr[4];
    float nv = fmaxf(ws[WS_COUNT], 1.f);
    float acc = 0.f;
    for (int j = t; j < KC; j += 256) {
        float p = ws[WS_COUNTS + j] / nv;
        acc = fmaf(p, logf(p + 1e-10f), acc);
    }
    #pragma unroll
    for (int off = 32; off > 0; off >>= 1) acc += __shfl_down(acc, off, 64);
    if ((t & 63) == 0) wr[t >> 6] = acc;
    __syncthreads();
    if (t == 0) {
        float ent = wr[0] + wr[1] + wr[2] + wr[3];
        float loss = ws[WS_LOSS] / (nv * (float)DIM);
        out[LOSS0_OFF] = loss;
        out[LOSS1_OFF] = loss;
        out[PERP_OFF] = expf(-ent);
    }
}

// ---------------------------------------------------------------- launch
extern "C" void kernel_launch(void* const* d_in, const int* in_sizes, int n_in,
                              void* d_out, int out_size, void* d_ws, size_t ws_size,
                              hipStream_t stream) {
    const float* x     = (const float*)d_in[0];
    const int*   amask = (const int*)d_in[1];
    const float* e     = (const float*)d_in[2];
    const float* gamma = (const float*)d_in[3];
    const float* beta  = (const float*)d_in[4];
    float* out = (float*)d_out;
    float* ws  = (float*)d_ws;

    size_t need_xq = (size_t)(WS_XQ + BN) * sizeof(float);           // ~2.52 MB
    size_t need_mk = (size_t)(WS_MINKEY + 2 * BN) * sizeof(float);   // ~2.39 MB
    size_t need_pk = (size_t)(WS_ETX + KC * DIM) * sizeof(float);    // ~2.03 MB
    size_t need_et = (size_t)(WS_ET_LEG + KC * DIM) * sizeof(float); // ~1.03 MB
    int use_pk = ws_size >= need_pk;
    int use_mk = use_pk && (ws_size >= need_mk);
    int use_pa = use_pk && use_mk;   // pre-packed A lives in out's QX region
    int use_xq = use_pa && (ws_size >= need_xq);
    int use_et = use_mk ? 0 : (use_pk ? 1 : (ws_size >= need_et ? 1 : 0));
    int et_off = use_pk ? WS_ETX : WS_ET_LEG;

    (void)hipMemsetAsync(d_ws, 0, 32768, stream);
    if (use_mk)
        (void)hipMemsetAsync((char*)d_ws + (size_t)WS_MINKEY * 4, 0xFF,
                             (size_t)BN * 8, stream);

    k_pre<<<324, 256, 0, stream>>>(x, amask, e, ws, use_et, use_pk, et_off);
    if (use_pa)
        k_packA<<<BN / 128, 512, 0, stream>>>(x, gamma, beta, ws, out, use_xq);
    k_main_mfma<<<256 * NSLICE, 512, 0, stream>>>(x, amask, e, gamma, beta, ws,
                                                  out, use_pk, use_mk, use_pa);
    if (!use_mk)
        k_merge<<<BN / 256, 256, 0, stream>>>(amask, ws, out);
    k_epi<<<BN / 32, 256, 0, stream>>>(x, amask, e, gamma, beta, ws, out,
                                       use_et, et_off, use_mk, use_xq);
    k_final<<<1, 256, 0, stream>>>(ws, out);
}

// Round 16
// 209.184 us; speedup vs baseline: 1.5509x; 1.0148x over previous
//
#include <hip/hip_runtime.h>
#include <math.h>

// Problem constants
#define BN   32768
#define DIM  256
#define KC   1024
#define BN_EPS 1e-5f

// Output layout (floats) in d_out
#define QX_SIZE   (BN * DIM)
#define LOSS0_OFF (QX_SIZE)
#define LOSS1_OFF (QX_SIZE + 1)
#define IDX_OFF   (QX_SIZE + 2)
#define PERP_OFF  (QX_SIZE + 2 + BN)

// Fallback scratch partials in the (later overwritten) QX region of out:
#define PART_V 0             // [NSLICE][BN] slice-min values
#define PART_I (NSLICE * BN) // [NSLICE][BN] slice-argmin indices (as float)
// use_pa path: QX region instead holds pre-packed A fragments (32 MB exact),
// written by k_packA, read by k_main, overwritten with q by k_epi.

// Workspace (float offsets)
#define WS_SUM    0     // 256
#define WS_SUMSQ  256   // 256
#define WS_COUNT  512   // 1
#define WS_LOSS   513   // 1
#define WS_COUNTS 1024  // 1024 (float counts -> perplexity)
#define WS_CNORM  3072  // 1024
#define WS_PK     8192                  // packed B chunks, 262144 floats (1MB)
#define WS_ETX    (8192 + 262144)       // eT [K][D] f32 (fallback only)
#define WS_MINKEY (8192 + 262144 + 262144) // [BN] u64 argmin keys
#define WS_XQ     (WS_MINKEY + 2 * BN)  // [BN] per-row |xb|^2 (fp32)
#define WS_ET_LEG 8192                  // eT offset in legacy layout

#define NSLICE 4
#define SLICEK (KC / NSLICE)            // 256 codes per slice
#define NGRP   (SLICEK / 64)            // 4 code-groups of 64 per slice

typedef short bf16x8  __attribute__((ext_vector_type(8)));
typedef float f32x4   __attribute__((ext_vector_type(4)));
typedef float fvec4   __attribute__((ext_vector_type(4)));
typedef int   int4v   __attribute__((ext_vector_type(4)));
typedef unsigned long long u64;

static __device__ inline unsigned short f2bf(float f) {
    unsigned int u = __float_as_uint(f);
    return (unsigned short)((u + 0x7FFFu + ((u >> 16) & 1u)) >> 16);
}
static __device__ inline fvec4 nt_ld4(const void* p) {
    return __builtin_nontemporal_load((const fvec4*)p);
}
static __device__ inline void nt_st(float* p, float v) {
    __builtin_nontemporal_store(v, p);
}
// order-preserving float <-> u32 (for atomicMin argmin keys)
static __device__ inline unsigned enc_f32(float f) {
    unsigned u = __float_as_uint(f);
    return (u & 0x80000000u) ? ~u : (u | 0x80000000u);
}
static __device__ inline float dec_f32(unsigned k) {
    return __uint_as_float((k & 0x80000000u) ? (k ^ 0x80000000u) : ~k);
}

// ---------------------------------------------------------------- kernel 1
// Blocks 0..255: masked stats. 256..259: cnorm. 260..323: transpose + pack.
__global__ __launch_bounds__(256) void k_pre(const float* __restrict__ x,
                                             const int* __restrict__ mask,
                                             const float* __restrict__ e,
                                             float* __restrict__ ws,
                                             int use_et, int use_pk, int et_off) {
    int t = threadIdx.x;
    int b = blockIdx.x;
    if (b >= 260) {                        // transpose tiles 64d x 64k
        if (!use_et && !use_pk) return;
        int b2 = b - 260;
        int d0 = (b2 >> 4) * 64;
        int k0 = (b2 & 15) * 64;
        __shared__ float tile[64][65];
        int c = t & 63;
        int rq = t >> 6;
        #pragma unroll
        for (int p = 0; p < 16; ++p) {
            int dd = p * 4 + rq;
            tile[dd][c] = e[(size_t)(d0 + dd) * KC + k0 + c];
        }
        __syncthreads();
        if (use_et) {
            #pragma unroll
            for (int p = 0; p < 16; ++p) {
                int kk = p * 4 + rq;
                nt_st(&ws[et_off + (size_t)(k0 + kk) * DIM + d0 + c],
                      tile[c][kk]);
            }
        }
        if (use_pk) {
            // Pack chunk-ordered B (bit-identical truncate split).
            char* pk = (char*)(ws + WS_PK);
            int lane2 = t & 63;
            int fgrp = t >> 6;
            int quad2 = lane2 >> 4, col2 = lane2 & 15;
            int G = b2 & 15;
            #pragma unroll
            for (int p = 0; p < 4; ++p) {
                int fi = fgrp * 4 + p;
                int kcl = fi >> 3;
                int nt = (fi >> 1) & 3;
                int h = fi & 1;
                int kcg = (b2 >> 4) * 2 + kcl;
                bf16x8 ov;
                #pragma unroll
                for (int j = 0; j < 8; ++j) {
                    float v = tile[kcl * 32 + quad2 * 8 + j][nt * 16 + col2];
                    unsigned u = __float_as_uint(v);
                    if (h == 0) {
                        ov[j] = (short)(u >> 16);
                    } else {
                        float lf = v - __uint_as_float(u & 0xffff0000u);
                        ov[j] = (short)(__float_as_uint(lf) >> 16);
                    }
                }
                size_t off = ((size_t)((G * 8 + kcg) * 8 + nt * 2 + h) << 10)
                             + (size_t)lane2 * 16;
                *(bf16x8*)(pk + off) = ov;
            }
        }
        return;
    }
    if (b >= 256) {                        // cnorm
        int k = (b - 256) * 256 + t;
        float acc = 0.f;
        #pragma unroll 8
        for (int d = 0; d < DIM; ++d) {
            float v = e[(size_t)d * KC + k];
            acc = fmaf(v, v, acc);
        }
        ws[WS_CNORM + k] = acc;
        return;
    }
    __shared__ float s4[4 * 256];
    __shared__ float q4[4 * 256];
    __shared__ float cntS[4];
    int c4 = t & 63;
    int rsub = t >> 6;
    float s0=0.f,s1=0.f,s2=0.f,s3=0.f, q0=0.f,q1=0.f,q2=0.f,q3=0.f, cnt=0.f;
    int rbase = b * 4 + rsub;
    for (int i = 0; i < 32; ++i) {
        int r = rbase + i * 1024;
        float m = (float)mask[r];
        fvec4 v = nt_ld4(&x[(size_t)r * DIM + c4 * 4]);
        cnt += m;
        float m0 = m*v.x, m1 = m*v.y, m2 = m*v.z, m3 = m*v.w;
        s0 += m0; s1 += m1; s2 += m2; s3 += m3;
        q0 = fmaf(m0, v.x, q0); q1 = fmaf(m1, v.y, q1);
        q2 = fmaf(m2, v.z, q2); q3 = fmaf(m3, v.w, q3);
    }
    int f = c4 * 4;
    s4[rsub * 256 + f + 0] = s0; s4[rsub * 256 + f + 1] = s1;
    s4[rsub * 256 + f + 2] = s2; s4[rsub * 256 + f + 3] = s3;
    q4[rsub * 256 + f + 0] = q0; q4[rsub * 256 + f + 1] = q1;
    q4[rsub * 256 + f + 2] = q2; q4[rsub * 256 + f + 3] = q3;
    if (c4 == 0) cntS[rsub] = cnt;
    __syncthreads();
    float stot = s4[t] + s4[256 + t] + s4[512 + t] + s4[768 + t];
    float qtot = q4[t] + q4[256 + t] + q4[512 + t] + q4[768 + t];
    atomicAdd(&ws[WS_SUM + t], stot);
    atomicAdd(&ws[WS_SUMSQ + t], qtot);
    if (t == 0)
        atomicAdd(&ws[WS_COUNT], cntS[0] + cntS[1] + cntS[2] + cntS[3]);
}

// ---------------------------------------------------------------- kernel 2a
// Pre-pack A fragments ONCE: compute xb, bit-identical f2bf hi/lo split,
// write MFMA-fragment-ordered A into out's QX region (32 MB). Also (use_xq)
// accumulate per-row |xb|^2 (fp32, pre-rounding) into ws so k_epi's loss
// needs NO x re-read: loss_row = |xb|^2 + (|q|^2 - 2<xb,q>) = xq + score.
__global__ __launch_bounds__(512) void k_packA(
        const float* __restrict__ x, const float* __restrict__ gamma,
        const float* __restrict__ beta, float* __restrict__ ws,
        float* __restrict__ out, int use_xq) {
    __shared__ float muS[DIM], scS[DIM], btS[DIM];
    const int tid = threadIdx.x;
    const int row0 = blockIdx.x * 128;
    const int w = tid >> 6;
    const int lane = tid & 63;
    const int quad = lane >> 4;
    const int col0 = lane & 15;
    if (tid < 256) {
        float cnt = ws[WS_COUNT];
        float nv = fmaxf(cnt, 1.f);
        float mu = ws[WS_SUM + tid] / nv;
        float var = ws[WS_SUMSQ + tid] / nv - mu * mu;
        var = fmaxf(var, 0.f);
        muS[tid] = mu;
        scS[tid] = rsqrtf(var + BN_EPS) * gamma[tid];
        btS[tid] = beta[tid];
    }
    __syncthreads();
    const float* xr = x + (size_t)(row0 + w * 16 + col0) * DIM;
    char* pa = (char*)out + (size_t)(blockIdx.x * 8 + w) * 16384;
    float xq = 0.f;
    #pragma unroll
    for (int kc = 0; kc < 8; ++kc) {
        int k0 = kc * 32 + quad * 8;
        fvec4 v0 = nt_ld4(xr + k0);
        fvec4 v1 = nt_ld4(xr + k0 + 4);
        float xv[8] = {v0.x, v0.y, v0.z, v0.w, v1.x, v1.y, v1.z, v1.w};
        bf16x8 hv, lv;
        #pragma unroll
        for (int j = 0; j < 8; ++j) {
            float xb = fmaf(xv[j] - muS[k0 + j], scS[k0 + j], btS[k0 + j]);
            xq = fmaf(xb, xb, xq);
            unsigned short h = f2bf(xb);
            float hf = __uint_as_float((unsigned)h << 16);
            hv[j] = (short)h;
            lv[j] = (short)f2bf(xb - hf);
        }
        __builtin_nontemporal_store(hv,
            (bf16x8*)(pa + (kc * 2 + 0) * 1024 + lane * 16));
        __builtin_nontemporal_store(lv,
            (bf16x8*)(pa + (kc * 2 + 1) * 1024 + lane * 16));
    }
    if (use_xq) {
        // full-row |xb|^2: sum across the 4 quads sharing a row
        xq += __shfl_xor(xq, 16, 64);
        xq += __shfl_xor(xq, 32, 64);
        if (quad == 0)
            ws[WS_XQ + row0 + w * 16 + col0] = xq;
    }
}

// ---------------------------------------------------------------- kernel 3
// MFMA main, 4-way codebook-sliced (R12/R15 structure — the measured
// feasibility notch: (512,4), VGPR=64, 2 blocks/CU; R13 code-split and
// R14 (512,6) both regressed). 512 threads, 128 rows/block, slice = 256
// codes. Grid 1024. Chunk = 8KB, 4-slot LDS ring, depth-2, vmcnt(2).
// use_pa: A pre-packed in out's QX region.
// XCD-AWARE REMAP (T1): the 4 slice-blocks sharing one rb's 128KB A panel
// previously landed on 4 different XCD L2s (bid round-robin) -> FETCH=70MB.
// Remap rb = (bid&7)*32 + (bid>>5), s = (bid>>3)&3: same-rb blocks are
// spaced 8 apart (same XCD, temporally adjacent) -> A fetched once per L2.
// Cross-slice merge: atomicMin(u64 key).

#define CHUNK_COMPUTE(slot, kcc)                                             \
    {                                                                        \
        const char* bufb = &Bs[(slot) * 8192];                               \
        __builtin_amdgcn_s_setprio(1);                                       \
        _Pragma("unroll")                                                    \
        for (int nt = 0; nt < 4; ++nt) {                                     \
            bf16x8 bh = *(const bf16x8*)(bufb + (nt * 2 + 0) * 1024 + lane * 16); \
            bf16x8 bl = *(const bf16x8*)(bufb + (nt * 2 + 1) * 1024 + lane * 16); \
            acc[nt] = __builtin_amdgcn_mfma_f32_16x16x32_bf16(ah[kcc], bh, acc[nt], 0, 0, 0); \
            acc[nt] = __builtin_amdgcn_mfma_f32_16x16x32_bf16(ah[kcc], bl, acc[nt], 0, 0, 0); \
            acc[nt] = __builtin_amdgcn_mfma_f32_16x16x32_bf16(al[kcc], bh, acc[nt], 0, 0, 0); \
        }                                                                    \
        __builtin_amdgcn_s_setprio(0);                                       \
    }

#define SCORE_MERGE(gg)                                                      \
    {                                                                        \
        _Pragma("unroll")                                                    \
        for (int r = 0; r < 4; ++r) {                                        \
            float v = 3.4e38f; int ii = 0;                                   \
            _Pragma("unroll")                                                \
            for (int nt = 0; nt < 4; ++nt) {                                 \
                int kl = (gg) * 64 + nt * 16 + col0;                         \
                float sc = fmaf(-2.f, acc[nt][r], cnS[kl]);                  \
                if (sc < v) { v = sc; ii = kl; }                             \
            }                                                                \
            _Pragma("unroll")                                                \
            for (int m2 = 1; m2 < 16; m2 <<= 1) {                            \
                float v2 = __shfl_xor(v, m2, 64);                            \
                int   i2 = __shfl_xor(ii, m2, 64);                           \
                if (v2 < v || (v2 == v && i2 < ii)) { v = v2; ii = i2; }     \
            }                                                                \
            if (v < bv[r] || (v == bv[r] && ii < bi_[r])) {                  \
                bv[r] = v; bi_[r] = ii;                                      \
            }                                                                \
        }                                                                    \
        _Pragma("unroll")                                                    \
        for (int nt = 0; nt < 4; ++nt)                                       \
            acc[nt] = (f32x4){0.f, 0.f, 0.f, 0.f};                           \
    }

__global__ __launch_bounds__(512, 4) void k_main_mfma(
        const float* __restrict__ x, const int* __restrict__ mask,
        const float* __restrict__ e, const float* __restrict__ gamma,
        const float* __restrict__ beta,
        float* __restrict__ ws, float* __restrict__ out,
        int use_pk, int use_mk, int use_pa) {
    __shared__ __align__(16) char Bs[4 * 8192];   // 32 KB B ring
    __shared__ float muS[DIM], scS[DIM], btS[DIM];
    __shared__ float cnS[SLICEK];

    const int tid = threadIdx.x;
    // XCD-aware remap (bijective on 1024 = 8 x 32 x 4)
    const int bid = blockIdx.x;
    const int rb = (bid & 7) * 32 + (bid >> 5);
    const int s = (bid >> 3) & 3;        // codebook slice
    const int row0 = rb * 128;
    const int w = tid >> 6;              // 0..7
    const int lane = tid & 63;
    const int quad = lane >> 4;
    const int col0 = lane & 15;

    if (!use_pa && tid < 256) {
        float cnt = ws[WS_COUNT];
        float nv = fmaxf(cnt, 1.f);
        float mu = ws[WS_SUM + tid] / nv;
        float var = ws[WS_SUMSQ + tid] / nv - mu * mu;
        var = fmaxf(var, 0.f);
        muS[tid] = mu;
        scS[tid] = rsqrtf(var + BN_EPS) * gamma[tid];
        btS[tid] = beta[tid];
    }
    if (tid < SLICEK)
        cnS[tid] = ws[WS_CNORM + s * SLICEK + tid];
    __syncthreads();

    // ---- A fragments in registers: wave w rows row0+w*16+col0
    bf16x8 ah[8], al[8];
    if (use_pa) {
        const char* pa = (const char*)out + (size_t)(rb * 8 + w) * 16384;
        #pragma unroll
        for (int kc = 0; kc < 8; ++kc) {
            ah[kc] = *(const bf16x8*)(pa + (kc * 2 + 0) * 1024 + lane * 16);
            al[kc] = *(const bf16x8*)(pa + (kc * 2 + 1) * 1024 + lane * 16);
        }
    } else {
        const float* xr = x + (size_t)(row0 + w * 16 + col0) * DIM;
        #pragma unroll
        for (int kc = 0; kc < 8; ++kc) {
            int k0 = kc * 32 + quad * 8;
            fvec4 v0 = nt_ld4(xr + k0);
            fvec4 v1 = nt_ld4(xr + k0 + 4);
            float xv[8] = {v0.x, v0.y, v0.z, v0.w, v1.x, v1.y, v1.z, v1.w};
            bf16x8 hv, lv;
            #pragma unroll
            for (int j = 0; j < 8; ++j) {
                float xb = fmaf(xv[j] - muS[k0 + j], scS[k0 + j], btS[k0 + j]);
                unsigned short h = f2bf(xb);
                float hf = __uint_as_float((unsigned)h << 16);
                hv[j] = (short)h;
                lv[j] = (short)f2bf(xb - hf);
            }
            ah[kc] = hv;
            al[kc] = lv;
        }
    }
    // retire A loads so the counted-vmcnt math sees only stage loads
    asm volatile("s_waitcnt vmcnt(0)" ::: "memory");
    __builtin_amdgcn_sched_barrier(0);

    f32x4 acc[4];
    #pragma unroll
    for (int nt = 0; nt < 4; ++nt)
        acc[nt] = (f32x4){0.f, 0.f, 0.f, 0.f};
    float bv[4] = {3.4e38f, 3.4e38f, 3.4e38f, 3.4e38f};
    int   bi_[4] = {0, 0, 0, 0};

    if (use_pk) {
        const char* pkb = (const char*)(ws + WS_PK)
                          + (size_t)s * (NGRP * 8 * 8192);
        auto stage = [&](int c2, int slot) {
            const char* src = pkb + (size_t)c2 * 8192 + w * 1024 + lane * 16;
            char* dst = &Bs[slot * 8192 + w * 1024];
            __builtin_amdgcn_global_load_lds(
                (const __attribute__((address_space(1))) void*)src,
                (__attribute__((address_space(3))) void*)dst, 16, 0, 0);
        };
        stage(0, 0);
        stage(1, 1);
        for (int g = 0; g < NGRP - 1; ++g) {
            #pragma unroll
            for (int kc = 0; kc < 8; ++kc) {
                stage(g * 8 + kc + 2, (kc + 2) & 3);
                asm volatile("s_waitcnt vmcnt(2)" ::: "memory");
                __builtin_amdgcn_s_barrier();
                __builtin_amdgcn_sched_barrier(0);
                CHUNK_COMPUTE(kc & 3, kc);
            }
            SCORE_MERGE(g);
        }
        {   // last group, counted drain
            #pragma unroll
            for (int kc = 0; kc < 8; ++kc) {
                if (kc < 6) {
                    stage((NGRP - 1) * 8 + kc + 2, (kc + 2) & 3);
                    asm volatile("s_waitcnt vmcnt(2)" ::: "memory");
                } else if (kc == 6) {
                    asm volatile("s_waitcnt vmcnt(1)" ::: "memory");
                } else {
                    asm volatile("s_waitcnt vmcnt(0)" ::: "memory");
                }
                __builtin_amdgcn_s_barrier();
                __builtin_amdgcn_sched_barrier(0);
                CHUNK_COMPUTE(kc & 3, kc);
            }
            SCORE_MERGE(NGRP - 1);
        }
    } else {
        // fallback: scattered loads from e (slice-local), in-reg split
        for (int g = 0; g < NGRP; ++g) {
            #pragma unroll
            for (int kc = 0; kc < 8; ++kc) {
                const float* ep = e + (size_t)(kc * 32 + quad * 8) * KC
                                    + s * SLICEK + g * 64 + col0;
                #pragma unroll
                for (int nt = 0; nt < 4; ++nt) {
                    const float* epn = ep + nt * 16;
                    float bvv[8];
                    #pragma unroll
                    for (int j = 0; j < 8; ++j)
                        bvv[j] = epn[(size_t)j * KC];
                    int4v hw, lw;
                    #pragma unroll
                    for (int p = 0; p < 4; ++p) {
                        unsigned u0 = __float_as_uint(bvv[2 * p]);
                        unsigned u1 = __float_as_uint(bvv[2 * p + 1]);
                        hw[p] = (int)__builtin_amdgcn_perm(u1, u0, 0x07060302u);
                        float l0 = bvv[2 * p]     - __uint_as_float(u0 & 0xffff0000u);
                        float l1 = bvv[2 * p + 1] - __uint_as_float(u1 & 0xffff0000u);
                        lw[p] = (int)__builtin_amdgcn_perm(__float_as_uint(l1),
                                                           __float_as_uint(l0),
                                                           0x07060302u);
                    }
                    bf16x8 bh = __builtin_bit_cast(bf16x8, hw);
                    bf16x8 bl = __builtin_bit_cast(bf16x8, lw);
                    acc[nt] = __builtin_amdgcn_mfma_f32_16x16x32_bf16(ah[kc], bh, acc[nt], 0, 0, 0);
                    acc[nt] = __builtin_amdgcn_mfma_f32_16x16x32_bf16(ah[kc], bl, acc[nt], 0, 0, 0);
                    acc[nt] = __builtin_amdgcn_mfma_f32_16x16x32_bf16(al[kc], bh, acc[nt], 0, 0, 0);
                }
            }
            SCORE_MERGE(g);
        }
    }

    // ---- per-wave result: lanes col0==0 own 4 rows each
    if (col0 == 0) {
        if (use_mk) {
            u64* mk = (u64*)(ws + WS_MINKEY);
            #pragma unroll
            for (int r = 0; r < 4; ++r) {
                int rl = w * 16 + quad * 4 + r;
                u64 key = ((u64)enc_f32(bv[r]) << 32)
                          | (unsigned)(s * SLICEK + bi_[r]);
                atomicMin(&mk[row0 + rl], key);
            }
        } else {
            #pragma unroll
            for (int r = 0; r < 4; ++r) {
                int rl = w * 16 + quad * 4 + r;
                out[PART_V + s * BN + row0 + rl] = bv[r];
                out[PART_I + s * BN + row0 + rl] = (float)(s * SLICEK + bi_[r]);
            }
        }
    }
}

// ---------------------------------------------------------------- kernel 3m
// Fallback only: merge slice partials -> final idx + counts.
__global__ __launch_bounds__(256) void k_merge(const int* __restrict__ mask,
                                               float* __restrict__ ws,
                                               float* __restrict__ out) {
    int row = blockIdx.x * 256 + threadIdx.x;
    float bvv = out[PART_V + row];
    int bii = (int)out[PART_I + row];
    #pragma unroll
    for (int s = 1; s < NSLICE; ++s) {
        float v = out[PART_V + s * BN + row];
        int i = (int)out[PART_I + s * BN + row];
        if (v < bvv || (v == bvv && i < bii)) { bvv = v; bii = i; }
    }
    int m = mask[row];
    out[IDX_OFF + row] = m ? (float)bii : -1.0f;
    if (m) atomicAdd(&ws[WS_COUNTS + bii], 1.0f);
}

// ---------------------------------------------------------------- kernel 3b
// Streaming epilogue, 32 rows/block, grid 1024. use_xq path: NO x re-read —
// loss_row = xq[row] + dec(score); only keys/mask/xq reads + broadcast
// e-gather + NT q-write. Counts via per-block LDS histogram (hot-address
// global atomics were the ~100us wall); q-gather idx-reuse cache.
__global__ __launch_bounds__(256) void k_epi(
        const float* __restrict__ x, const int* __restrict__ mask,
        const float* __restrict__ e, const float* __restrict__ gamma,
        const float* __restrict__ beta,
        const float* __restrict__ ws, float* __restrict__ out,
        int use_et, int et_off, int use_mk, int use_xq) {
    __shared__ __align__(16) float muS[DIM], scS[DIM], btS[DIM];
    __shared__ int   histC[KC];
    __shared__ float wred[4];
    const int tid = threadIdx.x;
    const int row0 = blockIdx.x * 32;
    const int w = tid >> 6;
    const int lane = tid & 63;
    if (!use_xq) {
        float cnt = ws[WS_COUNT];
        float nv = fmaxf(cnt, 1.f);
        float mu = ws[WS_SUM + tid] / nv;
        float var = ws[WS_SUMSQ + tid] / nv - mu * mu;
        var = fmaxf(var, 0.f);
        muS[tid] = mu;
        scS[tid] = rsqrtf(var + BN_EPS) * gamma[tid];
        btS[tid] = beta[tid];
    }
    #pragma unroll
    for (int j = 0; j < KC / 256; ++j)
        histC[j * 256 + tid] = 0;
    __syncthreads();

    // this wave's 8 row keys + masks (+xq) (coalesced, lanes 0..7)
    u64 mykey = 0; int mym = 0; float myxq = 0.f;
    if (use_mk && lane < 8) {
        const u64* mk = (const u64*)(ws + WS_MINKEY);
        mykey = mk[row0 + w * 8 + lane];
        mym = mask[row0 + w * 8 + lane];
        if (use_xq) myxq = ws[WS_XQ + row0 + w * 8 + lane];
    }

    const int d0 = lane * 4;
    const float* et = ws + et_off;
    float lacc = 0.f;
    int pidx = -1;
    fvec4 g = (fvec4){0.f, 0.f, 0.f, 0.f};
    if (use_xq) {
        // ---- no-x path: loss from xq + decoded score
        #pragma unroll
        for (int rr = 0; rr < 8; ++rr) {
            const int row = row0 + w * 8 + rr;
            u64 k = __shfl(mykey, rr, 64);
            int m = __shfl(mym, rr, 64);
            int idx = (int)(unsigned)(k & 0xFFFFFFFFull);
            if (lane == 0) {
                out[IDX_OFF + row] = m ? (float)idx : -1.0f;
                if (m) {
                    atomicAdd(&histC[idx], 1);
                    float score = dec_f32((unsigned)(k >> 32));
                    lacc += __shfl(myxq, rr, 64) + score;
                }
            }
            if (idx != pidx) {          // wave-uniform (idx via shfl)
                g.x = e[(size_t)(d0 + 0) * KC + idx];
                g.y = e[(size_t)(d0 + 1) * KC + idx];
                g.z = e[(size_t)(d0 + 2) * KC + idx];
                g.w = e[(size_t)(d0 + 3) * KC + idx];
                pidx = idx;
            }
            const float fm = (float)m;
            fvec4 q = (fvec4){fm * g.x, fm * g.y, fm * g.z, fm * g.w};
            __builtin_nontemporal_store(q,
                (fvec4*)&out[(size_t)row * DIM + d0]);
        }
        if (lane == 0) wred[w] = lacc;
    } else {
        fvec4 mu4 = *(const fvec4*)&muS[d0];
        fvec4 sc4 = *(const fvec4*)&scS[d0];
        fvec4 bt4 = *(const fvec4*)&btS[d0];
        #pragma unroll
        for (int rr = 0; rr < 8; ++rr) {
            const int row = row0 + w * 8 + rr;
            int m, idx;
            if (use_mk) {
                u64 k = __shfl(mykey, rr, 64);
                m = __shfl(mym, rr, 64);
                idx = (int)(unsigned)(k & 0xFFFFFFFFull);
                if (lane == 0) {
                    out[IDX_OFF + row] = m ? (float)idx : -1.0f;
                    if (m) atomicAdd(&histC[idx], 1);
                }
            } else {
                m = mask[row];
                idx = m ? (int)out[IDX_OFF + row] : 0;
            }
            const float fm = (float)m;
            fvec4 xv = nt_ld4(&x[(size_t)row * DIM + d0]);
            if (idx != pidx) {
                if (use_mk || !use_et) {
                    g.x = e[(size_t)(d0 + 0) * KC + idx];
                    g.y = e[(size_t)(d0 + 1) * KC + idx];
                    g.z = e[(size_t)(d0 + 2) * KC + idx];
                    g.w = e[(size_t)(d0 + 3) * KC + idx];
                } else {
                    g = nt_ld4(&et[(size_t)idx * DIM + d0]);
                }
                pidx = idx;
            }
            fvec4 q;
            float dsum = 0.f;
            #pragma unroll
            for (int i = 0; i < 4; ++i) {
                float xb = fmaf(xv[i] - mu4[i], sc4[i], bt4[i]);
                float diff = xb - g[i];
                dsum = fmaf(diff, diff, dsum);
                q[i] = fm * g[i];
            }
            lacc = fmaf(fm, dsum, lacc);
            __builtin_nontemporal_store(q,
                (fvec4*)&out[(size_t)row * DIM + d0]);
        }
        #pragma unroll
        for (int off2 = 32; off2 > 0; off2 >>= 1)
            lacc += __shfl_down(lacc, off2, 64);
        if (lane == 0) wred[w] = lacc;
    }
    __syncthreads();
    if (use_mk) {
        #pragma unroll
        for (int j = 0; j < KC / 256; ++j) {
            int c = histC[j * 256 + tid];
            if (c > 0) atomicAdd((float*)&ws[WS_COUNTS + j * 256 + tid],
                                 (float)c);
        }
    }
    if (tid == 0)
        atomicAdd((float*)&ws[WS_LOSS], wred[0] + wred[1] + wred[2] + wred[3]);
}

// ---------------------------------------------------------------- kernel 4
__global__ __launch_bounds__(256) void k_final(const float* __restrict__ ws,
                                               float* __restrict__ out) {
    int t = threadIdx.x;
    __shared__ float wr[4];
    float nv = fmaxf(ws[WS_COUNT], 1.f);
    float acc = 0.f;
    for (int j = t; j < KC; j += 256) {
        float p = ws[WS_COUNTS + j] / nv;
        acc = fmaf(p, logf(p + 1e-10f), acc);
    }
    #pragma unroll
    for (int off = 32; off > 0; off >>= 1) acc += __shfl_down(acc, off, 64);
    if ((t & 63) == 0) wr[t >> 6] = acc;
    __syncthreads();
    if (t == 0) {
        float ent = wr[0] + wr[1] + wr[2] + wr[3];
        float loss = ws[WS_LOSS] / (nv * (float)DIM);
        out[LOSS0_OFF] = loss;
        out[LOSS1_OFF] = loss;
        out[PERP_OFF] = expf(-ent);
    }
}

// ---------------------------------------------------------------- launch
extern "C" void kernel_launch(void* const* d_in, const int* in_sizes, int n_in,
                              void* d_out, int out_size, void* d_ws, size_t ws_size,
                              hipStream_t stream) {
    const float* x     = (const float*)d_in[0];
    const int*   amask = (const int*)d_in[1];
    const float* e     = (const float*)d_in[2];
    const float* gamma = (const float*)d_in[3];
    const float* beta  = (const float*)d_in[4];
    float* out = (float*)d_out;
    float* ws  = (float*)d_ws;

    size_t need_xq = (size_t)(WS_XQ + BN) * sizeof(float);           // ~2.52 MB
    size_t need_mk = (size_t)(WS_MINKEY + 2 * BN) * sizeof(float);   // ~2.39 MB
    size_t need_pk = (size_t)(WS_ETX + KC * DIM) * sizeof(float);    // ~2.03 MB
    size_t need_et = (size_t)(WS_ET_LEG + KC * DIM) * sizeof(float); // ~1.03 MB
    int use_pk = ws_size >= need_pk;
    int use_mk = use_pk && (ws_size >= need_mk);
    int use_pa = use_pk && use_mk;   // pre-packed A lives in out's QX region
    int use_xq = use_pa && (ws_size >= need_xq);
    int use_et = use_mk ? 0 : (use_pk ? 1 : (ws_size >= need_et ? 1 : 0));
    int et_off = use_pk ? WS_ETX : WS_ET_LEG;

    (void)hipMemsetAsync(d_ws, 0, 32768, stream);
    if (use_mk)
        (void)hipMemsetAsync((char*)d_ws + (size_t)WS_MINKEY * 4, 0xFF,
                             (size_t)BN * 8, stream);

    k_pre<<<324, 256, 0, stream>>>(x, amask, e, ws, use_et, use_pk, et_off);
    if (use_pa)
        k_packA<<<BN / 128, 512, 0, stream>>>(x, gamma, beta, ws, out, use_xq);
    k_main_mfma<<<256 * NSLICE, 512, 0, stream>>>(x, amask, e, gamma, beta, ws,
                                                  out, use_pk, use_mk, use_pa);
    if (!use_mk)
        k_merge<<<BN / 256, 256, 0, stream>>>(amask, ws, out);
    k_epi<<<BN / 32, 256, 0, stream>>>(x, amask, e, gamma, beta, ws, out,
                                       use_et, et_off, use_mk, use_xq);
    k_final<<<1, 256, 0, stream>>>(ws, out);
}